// Round 3
// baseline (195.536 us; speedup 1.0000x reference)
//
#include <hip/hip_runtime.h>

#define BSZ 2
#define SEQ 2048
#define NH 16
#define DHD 64
#define HDIM 1024   // NH*DHD
#define FS 1024     // input feature size
#define MR (BSZ*SEQ) // 4096
#define L2E 1.4426950408889634f

typedef __bf16 bf16x8 __attribute__((ext_vector_type(8)));
typedef __bf16 bf16x2t __attribute__((ext_vector_type(2)));
typedef float f32x4 __attribute__((ext_vector_type(4)));
typedef unsigned short u16;
typedef unsigned int u32;

__device__ __forceinline__ u16 f2bf(float f) {
  u32 x = __float_as_uint(f);
  return (u16)((x + 0x7fffu + ((x >> 16) & 1u)) >> 16);
}

__device__ __forceinline__ u32 pack2bf(float a, float b) {
  bf16x2t t = {(__bf16)a, (__bf16)b};
  return __builtin_bit_cast(u32, t);
}

__device__ __forceinline__ void gload16(const void* g, void* l) {
  __builtin_amdgcn_global_load_lds(
      (const __attribute__((address_space(1))) u32*)g,
      (__attribute__((address_space(3))) u32*)l, 16, 0, 0);
}

// ---------------- cast fp32 -> bf16 (vectorized) ----------------
__global__ __launch_bounds__(256) void cast_k(const float* __restrict__ in,
                                              u16* __restrict__ out, int n4) {
  int i = blockIdx.x * 256 + threadIdx.x;
  const int st = gridDim.x * 256;
  for (; i < n4; i += st) {
    float4 v = ((const float4*)in)[i];
    ushort4 o;
    o.x = f2bf(v.x); o.y = f2bf(v.y); o.z = f2bf(v.z); o.w = f2bf(v.w);
    ((ushort4*)out)[i] = o;
  }
}

// ---------------- W[K][N] fp32 -> WT[N][K] bf16 ----------------
__global__ __launch_bounds__(256) void transw_k(const float* __restrict__ W,
                                                u16* __restrict__ WT) {
  __shared__ float t[32][33];
  const int tx = threadIdx.x, ty = threadIdx.y;
  const int c0 = blockIdx.x * 32, r0 = blockIdx.y * 32;
#pragma unroll
  for (int i = 0; i < 4; i++)
    t[ty + 8 * i][tx] = W[(size_t)(r0 + ty + 8 * i) * FS + c0 + tx];
  __syncthreads();
#pragma unroll
  for (int i = 0; i < 4; i++)
    WT[(size_t)(c0 + ty + 8 * i) * FS + r0 + tx] = f2bf(t[tx][ty + 8 * i]);
}

// ---------------- Vp[b][kv][h*64+d] bf16 -> VpT[(b*NH+h)*64+d][kv] bf16 ----
__global__ __launch_bounds__(256) void vtrans_k(const u16* __restrict__ Vp,
                                                u16* __restrict__ VpT) {
  __shared__ u16 tT[64 * 72];  // [d][kv], padded stride 72
  const int bid = blockIdx.x;
  const int kt = bid & 31;
  const int bh = bid >> 5;  // b*NH + h
  const int tid = threadIdx.x;
  const size_t src = (size_t)((bh >> 4) * SEQ + kt * 64) * HDIM + (size_t)(bh & 15) * DHD;
  {
    const int dd = (tid & 31) * 2;
    const int kvc = tid >> 5;
    u32 pk[8];
#pragma unroll
    for (int k = 0; k < 8; k++)
      pk[k] = *(const u32*)(Vp + src + (size_t)(kvc * 8 + k) * HDIM + dd);
    uint4 lo, hi;
    lo.x = (pk[0] & 0xffffu) | (pk[1] << 16);
    lo.y = (pk[2] & 0xffffu) | (pk[3] << 16);
    lo.z = (pk[4] & 0xffffu) | (pk[5] << 16);
    lo.w = (pk[6] & 0xffffu) | (pk[7] << 16);
    hi.x = (pk[0] >> 16) | (pk[1] & 0xffff0000u);
    hi.y = (pk[2] >> 16) | (pk[3] & 0xffff0000u);
    hi.z = (pk[4] >> 16) | (pk[5] & 0xffff0000u);
    hi.w = (pk[6] >> 16) | (pk[7] & 0xffff0000u);
    *(uint4*)&tT[(size_t)dd * 72 + kvc * 8] = lo;
    *(uint4*)&tT[(size_t)(dd + 1) * 72 + kvc * 8] = hi;
  }
  __syncthreads();
  const size_t dst = (size_t)bh * DHD * SEQ + (size_t)kt * 64;
#pragma unroll
  for (int i = 0; i < 2; i++) {
    const int r = (tid >> 3) + 32 * i;
    const int c = (tid & 7) * 8;
    *(uint4*)(VpT + dst + (size_t)r * SEQ + c) = *(const uint4*)&tT[r * 72 + c];
  }
}

// ---------------- GEMM: C[M][N] = (A[M][K] @ BT[N][K]^T + bias) * oscale ----
template <int OUTF32>
__global__ __launch_bounds__(256, 2) void gemm_k(
    const u16* __restrict__ A, const u16* __restrict__ BT,
    const float* __restrict__ bias, void* __restrict__ C,
    int Md, int Nd, int Kd, float oscale) {
  __shared__ u16 aL[128 * 64];
  __shared__ u16 bL[128 * 64];
  const int nt = Nd >> 7;
  const int m0 = (blockIdx.x / nt) << 7;
  const int n0 = (blockIdx.x % nt) << 7;
  const int tid = threadIdx.x, w = tid >> 6, lane = tid & 63;
  const int wr = ((w >> 1) << 6), wc = ((w & 1) << 6);
  const int li = lane & 15, g = lane >> 4;

  f32x4 acc[4][4];
#pragma unroll
  for (int i = 0; i < 4; i++)
#pragma unroll
    for (int j = 0; j < 4; j++) acc[i][j] = (f32x4){0.f, 0.f, 0.f, 0.f};

  for (int k0 = 0; k0 < Kd; k0 += 64) {
#pragma unroll
    for (int j = 0; j < 4; j++) {
      const int c = w * 4 + j;
      const int r = c * 8 + (lane >> 3);
      const int sc = (lane & 7) ^ (r & 7);
      gload16(A + (size_t)(m0 + r) * Kd + k0 + sc * 8, (char*)aL + c * 1024);
      gload16(BT + (size_t)(n0 + r) * Kd + k0 + sc * 8, (char*)bL + c * 1024);
    }
    __syncthreads();
    bf16x8 af[2][4], bfr[2][4];
#pragma unroll
    for (int ks = 0; ks < 2; ks++) {
#pragma unroll
      for (int mf = 0; mf < 4; mf++) {
        const int r = wr + mf * 16 + li;
        const int sl = (g + 4 * ks) ^ (r & 7);
        af[ks][mf] = *(const bf16x8*)((const char*)aL + r * 128 + sl * 16);
      }
#pragma unroll
      for (int nf = 0; nf < 4; nf++) {
        const int r = wc + nf * 16 + li;
        const int sl = (g + 4 * ks) ^ (r & 7);
        bfr[ks][nf] = *(const bf16x8*)((const char*)bL + r * 128 + sl * 16);
      }
    }
#pragma unroll
    for (int ks = 0; ks < 2; ks++)
#pragma unroll
      for (int mf = 0; mf < 4; mf++)
#pragma unroll
        for (int nf = 0; nf < 4; nf++)
          acc[mf][nf] = __builtin_amdgcn_mfma_f32_16x16x32_bf16(
              af[ks][mf], bfr[ks][nf], acc[mf][nf], 0, 0, 0);
    __syncthreads();
  }

#pragma unroll
  for (int mf = 0; mf < 4; mf++)
#pragma unroll
    for (int nf = 0; nf < 4; nf++) {
      const int n = n0 + wc + nf * 16 + li;
      const float bv = bias[n];
#pragma unroll
      for (int r4 = 0; r4 < 4; r4++) {
        const int m = m0 + wr + mf * 16 + g * 4 + r4;
        const float v = (acc[mf][nf][r4] + bv) * oscale;
        if (OUTF32)
          ((float*)C)[(size_t)m * Nd + n] = v;
        else
          ((u16*)C)[(size_t)m * Nd + n] = f2bf(v);
      }
    }
}

// ---------------- flash attention: wave-independent kv-split ---------------
// block = (b,h, 64 q); 4 waves; wave w handles kv tiles t == w (mod 4),
// KVBLK=32. No barriers in main loop; counted vmcnt prefetch; partial
// (m,l,O) per wave combined via LDS at the end.
__global__ __launch_bounds__(256, 2) void attn_k(
    const u16* __restrict__ Qp, const u16* __restrict__ Kp,
    const u16* __restrict__ VpT, u16* __restrict__ Hd) {
  extern __shared__ char pool[];  // 4 waves x 20KB = 80KB

  const int bid = blockIdx.x;
  const int swz = (bid & 7) * 128 + (bid >> 3);  // XCD swizzle (1024 % 8 == 0)
  const int qb = swz & 31;
  const int bh = swz >> 5;
  const int h = bh & 15;
  const int b = bh >> 4;
  const int tid = threadIdx.x, w = tid >> 6, lane = tid & 63;
  const int li = lane & 15, g = lane >> 4;
  const int q0 = qb << 6;
  const size_t qbase = (size_t)(b * SEQ + q0) * HDIM + (size_t)h * DHD;
  const size_t kbase = (size_t)(b * SEQ) * HDIM + (size_t)h * DHD;
  const size_t vtbase = (size_t)bh * DHD * SEQ;

  char* myK = pool + w * 20480;      // 2 x 4KB
  char* myV = myK + 8192;            // 2 x 4KB
  char* myP = myK + 16384;           // 4KB

  const int sw8k = ((lane & 7) ^ ((lane >> 3) & 7)) * 8;  // key = row&7
  const int sw8v = ((lane & 3) ^ ((lane >> 2) & 3)) * 8;  // key = row&3

  // ---- stage Q (8KB) cooperatively into pool[0..8192) ----
#pragma unroll
  for (int j = 0; j < 2; j++) {
    const int ch = w * 2 + j;
    const int qr = ch * 8 + (lane >> 3);
    gload16(Qp + qbase + (size_t)qr * HDIM + sw8k, pool + ch * 1024);
  }
  __syncthreads();
  bf16x8 qfr[4][2];
#pragma unroll
  for (int qf = 0; qf < 4; qf++)
#pragma unroll
    for (int ks = 0; ks < 2; ks++)
      qfr[qf][ks] = *(const bf16x8*)(pool + (16 * qf + li) * 128 +
                                     (((4 * ks + g) ^ (li & 7)) * 16));
  __syncthreads();  // wave 0's K region now free

  auto stageKV = [&](int t, int half) {
    const size_t kb = kbase + (size_t)(t * 32) * HDIM;
    const size_t vb = vtbase + (size_t)(t * 32);
    char* kd = myK + half * 4096;
    char* vd = myV + half * 4096;
#pragma unroll
    for (int j = 0; j < 4; j++) {
      const int r = j * 8 + (lane >> 3);
      gload16(Kp + kb + (size_t)r * HDIM + sw8k, kd + j * 1024);
    }
#pragma unroll
    for (int j = 0; j < 4; j++) {
      const int d = j * 16 + (lane >> 2);
      gload16(VpT + vb + (size_t)d * SEQ + sw8v, vd + j * 1024);
    }
  };

  float m_[4], l_[4], nm[4];
  f32x4 o[4][4];
#pragma unroll
  for (int qf = 0; qf < 4; qf++) {
    m_[qf] = -1e30f; l_[qf] = 0.f; nm[qf] = 0.f;
#pragma unroll
    for (int nf = 0; nf < 4; nf++) o[qf][nf] = (f32x4){0.f, 0.f, 0.f, 0.f};
  }

  stageKV(w, 0);

#pragma unroll 2
  for (int i = 0; i < 16; i++) {
    char* kc = myK + (i & 1) * 4096;
    char* vc = myV + (i & 1) * 4096;
    if (i + 1 < 16) {
      stageKV(w + 4 * (i + 1), (i + 1) & 1);
      asm volatile("s_waitcnt vmcnt(8)" ::: "memory");
    } else {
      asm volatile("s_waitcnt vmcnt(0)" ::: "memory");
    }
    __builtin_amdgcn_sched_barrier(0);

    // ---- S^T = K @ Q^T: lane holds S[kv=16c+4g+r4][q=16qf+li] ----
    bf16x8 kf[2][2];
#pragma unroll
    for (int c = 0; c < 2; c++)
#pragma unroll
      for (int ks = 0; ks < 2; ks++)
        kf[c][ks] = *(const bf16x8*)(kc + (16 * c + li) * 128 +
                                     (((4 * ks + g) ^ (li & 7)) * 16));
    f32x4 s[2][4];
#pragma unroll
    for (int c = 0; c < 2; c++)
#pragma unroll
      for (int qf = 0; qf < 4; qf++) s[c][qf] = (f32x4){0.f, 0.f, 0.f, 0.f};
    __builtin_amdgcn_s_setprio(1);
#pragma unroll
    for (int ks = 0; ks < 2; ks++)
#pragma unroll
      for (int c = 0; c < 2; c++)
#pragma unroll
        for (int qf = 0; qf < 4; qf++)
          s[c][qf] = __builtin_amdgcn_mfma_f32_16x16x32_bf16(
              kf[c][ks], qfr[qf][ks], s[c][qf], 0, 0, 0);
    __builtin_amdgcn_s_setprio(0);

    // ---- online softmax with defer-max (THR=8) ----
    float mx[4];
#pragma unroll
    for (int qf = 0; qf < 4; qf++) {
      float m0v = fmaxf(fmaxf(s[0][qf][0], s[0][qf][1]),
                        fmaxf(s[0][qf][2], s[0][qf][3]));
      float m1v = fmaxf(fmaxf(s[1][qf][0], s[1][qf][1]),
                        fmaxf(s[1][qf][2], s[1][qf][3]));
      float m = fmaxf(m0v, m1v);
      m = fmaxf(m, __shfl_xor(m, 16));
      m = fmaxf(m, __shfl_xor(m, 32));
      mx[qf] = m;
    }
    float growth = fmaxf(fmaxf(mx[0] - m_[0], mx[1] - m_[1]),
                         fmaxf(mx[2] - m_[2], mx[3] - m_[3]));
    if (__any(growth > 8.0f)) {
#pragma unroll
      for (int qf = 0; qf < 4; qf++) {
        const float mn = fmaxf(m_[qf], mx[qf]);
        const float sc = exp2f((m_[qf] - mn) * L2E);
        m_[qf] = mn;
        nm[qf] = -mn * L2E;
        l_[qf] *= sc;
#pragma unroll
        for (int nf = 0; nf < 4; nf++) o[qf][nf] *= sc;
      }
    }

    // ---- p = exp, row-sum, pack -> P LDS (swizzled) ----
#pragma unroll
    for (int qf = 0; qf < 4; qf++) {
      float pv[8];
      float rs = 0.f;
#pragma unroll
      for (int c = 0; c < 2; c++)
#pragma unroll
        for (int r4 = 0; r4 < 4; r4++) {
          const float p = exp2f(fmaf(s[c][qf][r4], L2E, nm[qf]));
          pv[c * 4 + r4] = p;
          rs += p;
        }
      rs += __shfl_xor(rs, 16);
      rs += __shfl_xor(rs, 32);
      l_[qf] += rs;
      char* prow = myP + (16 * qf + li) * 64;
#pragma unroll
      for (int c = 0; c < 2; c++) {
        uint2 d2;
        d2.x = pack2bf(pv[c * 4 + 0], pv[c * 4 + 1]);
        d2.y = pack2bf(pv[c * 4 + 2], pv[c * 4 + 3]);
        *(uint2*)(prow + (((4 * c + g) ^ (2 * (li & 3))) * 8)) = d2;
      }
    }

    // ---- O^T += V^T @ P^T ----
    bf16x8 vf[4], pf[4];
#pragma unroll
    for (int nf = 0; nf < 4; nf++)
      vf[nf] = *(const bf16x8*)(vc + (16 * nf + li) * 64 +
                                ((g ^ (li & 3)) * 16));
#pragma unroll
    for (int qf = 0; qf < 4; qf++)
      pf[qf] = *(const bf16x8*)(myP + (16 * qf + li) * 64 +
                                ((g ^ (li & 3)) * 16));
    __builtin_amdgcn_s_setprio(1);
#pragma unroll
    for (int qf = 0; qf < 4; qf++)
#pragma unroll
      for (int nf = 0; nf < 4; nf++)
        o[qf][nf] = __builtin_amdgcn_mfma_f32_16x16x32_bf16(
            vf[nf], pf[qf], o[qf][nf], 0, 0, 0);
    __builtin_amdgcn_s_setprio(0);
  }

  // ---- write partials to own LDS region (safe: wave-private) ----
#pragma unroll
  for (int qf = 0; qf < 4; qf++) {
    const int q = 16 * qf + li;
#pragma unroll
    for (int nf = 0; nf < 4; nf++)
      *(f32x4*)(myK + q * 256 + (((4 * nf + g) ^ li) * 16)) = o[qf][nf];
  }
  if (g == 0) {
#pragma unroll
    for (int qf = 0; qf < 4; qf++) {
      *(float*)(myP + (16 * qf + li) * 4) = m_[qf];
      *(float*)(myP + 256 + (16 * qf + li) * 4) = l_[qf];
    }
  }
  __syncthreads();

  // ---- combine 4 wave partials; thread (w2=tid>>6, lane) owns q=lane ----
  {
    const int q = lane;
    float mw[4], lw[4];
#pragma unroll
    for (int ww = 0; ww < 4; ww++) {
      mw[ww] = *(const float*)(pool + ww * 20480 + 16384 + q * 4);
      lw[ww] = *(const float*)(pool + ww * 20480 + 16384 + 256 + q * 4);
    }
    float ms = fmaxf(fmaxf(mw[0], mw[1]), fmaxf(mw[2], mw[3]));
    float fac[4], ls = 0.f;
#pragma unroll
    for (int ww = 0; ww < 4; ww++) {
      fac[ww] = exp2f((mw[ww] - ms) * L2E);
      ls += lw[ww] * fac[ww];
    }
    const float inv = 1.f / ls;
    u16* orow = Hd + (size_t)(b * SEQ + q0 + q) * HDIM + (size_t)h * DHD + w * 16;
#pragma unroll
    for (int i = 0; i < 4; i++) {
      f32x4 acc = (f32x4){0.f, 0.f, 0.f, 0.f};
#pragma unroll
      for (int ww = 0; ww < 4; ww++) {
        const f32x4 v = *(const f32x4*)(pool + ww * 20480 + q * 256 +
                                        (((4 * w + i) ^ (q & 15)) * 16));
        acc += v * fac[ww];
      }
      ushort4 ov;
      ov.x = f2bf(acc[0] * inv);
      ov.y = f2bf(acc[1] * inv);
      ov.z = f2bf(acc[2] * inv);
      ov.w = f2bf(acc[3] * inv);
      *(ushort4*)(orow + i * 4) = ov;
    }
  }
}

// ---------------- launch ----------------
extern "C" void kernel_launch(void* const* d_in, const int* in_sizes, int n_in,
                              void* d_out, int out_size, void* d_ws, size_t ws_size,
                              hipStream_t stream) {
  (void)in_sizes; (void)n_in; (void)out_size; (void)ws_size;
  const float* q_in = (const float*)d_in[0];
  const float* k_in = (const float*)d_in[1];
  const float* v_in = (const float*)d_in[2];
  const float* Wq_w = (const float*)d_in[3];
  const float* Wq_b = (const float*)d_in[4];
  const float* Wk_w = (const float*)d_in[5];
  const float* Wk_b = (const float*)d_in[6];
  const float* Wv_w = (const float*)d_in[7];
  const float* Wv_b = (const float*)d_in[8];
  const float* Wo_w = (const float*)d_in[9];
  const float* Wo_b = (const float*)d_in[10];

  char* ws = (char*)d_ws;
  size_t off = 0;
  auto alloc = [&](size_t n) {
    char* p = ws + off;
    off += (n + 255) & ~(size_t)255;
    return p;
  };
  u16* qb_ = (u16*)alloc((size_t)MR * FS * 2);
  u16* kb_ = (u16*)alloc((size_t)MR * FS * 2);
  u16* vb_ = (u16*)alloc((size_t)MR * FS * 2);
  u16* wqT = (u16*)alloc((size_t)FS * HDIM * 2);
  u16* wkT = (u16*)alloc((size_t)FS * HDIM * 2);
  u16* wvT = (u16*)alloc((size_t)FS * HDIM * 2);
  u16* woT = (u16*)alloc((size_t)HDIM * HDIM * 2);
  u16* Qp = (u16*)alloc((size_t)MR * HDIM * 2);
  u16* Kp = (u16*)alloc((size_t)MR * HDIM * 2);
  u16* Vp = (u16*)alloc((size_t)MR * HDIM * 2);
  u16* Hdp = (u16*)alloc((size_t)MR * HDIM * 2);
  u16* VpT = qb_;  // reuse: qb_ dead after Q projection GEMM

  const int n4 = MR * FS / 4;
  cast_k<<<2048, 256, 0, stream>>>(q_in, qb_, n4);
  cast_k<<<2048, 256, 0, stream>>>(k_in, kb_, n4);
  cast_k<<<2048, 256, 0, stream>>>(v_in, vb_, n4);

  dim3 tb(32, 8), tg(FS / 32, FS / 32);
  transw_k<<<tg, tb, 0, stream>>>(Wq_w, wqT);
  transw_k<<<tg, tb, 0, stream>>>(Wk_w, wkT);
  transw_k<<<tg, tb, 0, stream>>>(Wv_w, wvT);
  transw_k<<<tg, tb, 0, stream>>>(Wo_w, woT);

  const int gblocks = (MR / 128) * (HDIM / 128);
  gemm_k<0><<<gblocks, 256, 0, stream>>>(qb_, wqT, Wq_b, Qp, MR, HDIM, FS, 0.125f);
  gemm_k<0><<<gblocks, 256, 0, stream>>>(kb_, wkT, Wk_b, Kp, MR, HDIM, FS, 1.0f);
  gemm_k<0><<<gblocks, 256, 0, stream>>>(vb_, wvT, Wv_b, Vp, MR, HDIM, FS, 1.0f);

  vtrans_k<<<BSZ * NH * (SEQ / 64), 256, 0, stream>>>(Vp, VpT);

  attn_k<<<BSZ * NH * (SEQ / 64), 256, 81920, stream>>>(Qp, Kp, VpT, Hdp);

  gemm_k<1><<<gblocks, 256, 0, stream>>>(Hdp, woT, Wo_b, d_out, MR, HDIM, HDIM, 1.0f);
}

// Round 4
// 149.345 us; speedup vs baseline: 1.3093x; 1.3093x over previous
//
#include <hip/hip_runtime.h>

#define BSZ 2
#define SEQ 2048
#define NH 16
#define DHD 64
#define HDIM 1024   // NH*DHD
#define FS 1024     // input feature size
#define MR (BSZ*SEQ) // 4096
#define L2E 1.4426950408889634f

typedef __bf16 bf16x8 __attribute__((ext_vector_type(8)));
typedef __bf16 bf16x2t __attribute__((ext_vector_type(2)));
typedef float f32x4 __attribute__((ext_vector_type(4)));
typedef unsigned short u16;
typedef unsigned int u32;

__device__ __forceinline__ u16 f2bf(float f) {
  u32 x = __float_as_uint(f);
  return (u16)((x + 0x7fffu + ((x >> 16) & 1u)) >> 16);
}

__device__ __forceinline__ u32 pack2bf(float a, float b) {
  bf16x2t t = {(__bf16)a, (__bf16)b};
  return __builtin_bit_cast(u32, t);
}

__device__ __forceinline__ void gload16(const void* g, void* l) {
  __builtin_amdgcn_global_load_lds(
      (const __attribute__((address_space(1))) u32*)g,
      (__attribute__((address_space(3))) u32*)l, 16, 0, 0);
}

// ---------------- cast q,k,v fp32 -> bf16 (one launch; dsts contiguous) ----
__global__ __launch_bounds__(256) void cast3_k(const float* __restrict__ q,
                                               const float* __restrict__ k,
                                               const float* __restrict__ v,
                                               u16* __restrict__ dst, int n4) {
  int i = blockIdx.x * 256 + threadIdx.x;
  const int st = gridDim.x * 256;
  const int tot = 3 * n4;
  for (; i < tot; i += st) {
    const int arr = i >> 20;        // n4 == 1<<20
    const int idx = i & (n4 - 1);
    const float* src = arr == 0 ? q : arr == 1 ? k : v;
    float4 vv = ((const float4*)src)[idx];
    ushort4 o;
    o.x = f2bf(vv.x); o.y = f2bf(vv.y); o.z = f2bf(vv.z); o.w = f2bf(vv.w);
    ((ushort4*)dst)[i] = o;
  }
}

// ------- 4x W[K][N] fp32 -> WT[N][K] bf16 (one launch; dsts contiguous) ----
__global__ __launch_bounds__(256) void transw4_k(
    const float* __restrict__ W0, const float* __restrict__ W1,
    const float* __restrict__ W2, const float* __restrict__ W3,
    u16* __restrict__ WTbase) {
  __shared__ float t[32][33];
  const int z = blockIdx.z;
  const float* W = z == 0 ? W0 : z == 1 ? W1 : z == 2 ? W2 : W3;
  u16* WT = WTbase + (size_t)z * FS * HDIM;
  const int tx = threadIdx.x, ty = threadIdx.y;
  const int c0 = blockIdx.x * 32, r0 = blockIdx.y * 32;
#pragma unroll
  for (int i = 0; i < 4; i++)
    t[ty + 8 * i][tx] = W[(size_t)(r0 + ty + 8 * i) * FS + c0 + tx];
  __syncthreads();
#pragma unroll
  for (int i = 0; i < 4; i++)
    WT[(size_t)(c0 + ty + 8 * i) * FS + r0 + tx] = f2bf(t[tx][ty + 8 * i]);
}

// -------- grouped QKV projection GEMM: grid (256, 3) --------
// grp 0: Qp = (q@Wq + bq) * 0.125*L2E  (bf16, [m][n])
// grp 1: Kp = k@Wk + bk                (bf16, [m][n])
// grp 2: VpT = transpose-per-head of (v@Wv + bv)  (bf16, [(b,h,d)][kv])
__global__ __launch_bounds__(256, 2) void gemmQKV_k(
    const u16* __restrict__ Abase, const u16* __restrict__ WTbase,
    const float* __restrict__ bq, const float* __restrict__ bk,
    const float* __restrict__ bv, u16* __restrict__ QKbase,
    u16* __restrict__ VpT) {
  __shared__ u16 aL[128 * 64];
  __shared__ u16 bL[128 * 64];
  const int grp = blockIdx.y;
  const u16* A = Abase + (size_t)grp * MR * FS;
  const u16* BT = WTbase + (size_t)grp * FS * HDIM;
  const float* bias = grp == 0 ? bq : grp == 1 ? bk : bv;
  const int m0 = (blockIdx.x >> 3) << 7;
  const int n0 = (blockIdx.x & 7) << 7;
  const int tid = threadIdx.x, w = tid >> 6, lane = tid & 63;
  const int wr = ((w >> 1) << 6), wc = ((w & 1) << 6);
  const int li = lane & 15, g = lane >> 4;

  f32x4 acc[4][4];
#pragma unroll
  for (int i = 0; i < 4; i++)
#pragma unroll
    for (int j = 0; j < 4; j++) acc[i][j] = (f32x4){0.f, 0.f, 0.f, 0.f};

  for (int k0 = 0; k0 < FS; k0 += 64) {
#pragma unroll
    for (int j = 0; j < 4; j++) {
      const int c = w * 4 + j;
      const int r = c * 8 + (lane >> 3);
      const int sc = (lane & 7) ^ (r & 7);
      gload16(A + (size_t)(m0 + r) * FS + k0 + sc * 8, (char*)aL + c * 1024);
      gload16(BT + (size_t)(n0 + r) * FS + k0 + sc * 8, (char*)bL + c * 1024);
    }
    __syncthreads();
    bf16x8 af[2][4], bfr[2][4];
#pragma unroll
    for (int ks = 0; ks < 2; ks++) {
#pragma unroll
      for (int mf = 0; mf < 4; mf++) {
        const int r = wr + mf * 16 + li;
        const int sl = (g + 4 * ks) ^ (r & 7);
        af[ks][mf] = *(const bf16x8*)((const char*)aL + r * 128 + sl * 16);
      }
#pragma unroll
      for (int nf = 0; nf < 4; nf++) {
        const int r = wc + nf * 16 + li;
        const int sl = (g + 4 * ks) ^ (r & 7);
        bfr[ks][nf] = *(const bf16x8*)((const char*)bL + r * 128 + sl * 16);
      }
    }
    __builtin_amdgcn_s_setprio(1);
#pragma unroll
    for (int ks = 0; ks < 2; ks++)
#pragma unroll
      for (int mf = 0; mf < 4; mf++)
#pragma unroll
        for (int nf = 0; nf < 4; nf++)
          acc[mf][nf] = __builtin_amdgcn_mfma_f32_16x16x32_bf16(
              af[ks][mf], bfr[ks][nf], acc[mf][nf], 0, 0, 0);
    __builtin_amdgcn_s_setprio(0);
    __syncthreads();
  }

  if (grp < 2) {
    const float osc = grp == 0 ? 0.125f * L2E : 1.0f;
    u16* C = QKbase + (size_t)grp * MR * HDIM;
#pragma unroll
    for (int mf = 0; mf < 4; mf++)
#pragma unroll
      for (int nf = 0; nf < 4; nf++) {
        const int n = n0 + wc + nf * 16 + li;
        const float bvl = bias[n];
#pragma unroll
        for (int r4 = 0; r4 < 4; r4++) {
          const int m = m0 + wr + mf * 16 + g * 4 + r4;
          C[(size_t)m * HDIM + n] = f2bf((acc[mf][nf][r4] + bvl) * osc);
        }
      }
  } else {
    // V: write transposed per head -> VpT[((b*NH+h)*DHD+d)][kv]
#pragma unroll
    for (int mf = 0; mf < 4; mf++)
#pragma unroll
      for (int nf = 0; nf < 4; nf++) {
        const int n = n0 + wc + nf * 16 + li;
        const float bvl = bias[n];
        const int m = m0 + wr + mf * 16 + g * 4;
        const int bb = m >> 11, kv = m & 2047;
        ushort4 o;
        o.x = f2bf(acc[mf][nf][0] + bvl);
        o.y = f2bf(acc[mf][nf][1] + bvl);
        o.z = f2bf(acc[mf][nf][2] + bvl);
        o.w = f2bf(acc[mf][nf][3] + bvl);
        *(ushort4*)(VpT +
                    ((size_t)(bb * NH + (n >> 6)) * DHD + (n & 63)) * SEQ + kv) = o;
      }
  }
}

// ---------------- output GEMM: out[M][N] = Hd @ WoT^T + bo (fp32) ----------
__global__ __launch_bounds__(256, 2) void gemm_out_k(
    const u16* __restrict__ A, const u16* __restrict__ BT,
    const float* __restrict__ bias, float* __restrict__ C) {
  __shared__ u16 aL[128 * 64];
  __shared__ u16 bL[128 * 64];
  const int m0 = (blockIdx.x >> 3) << 7;
  const int n0 = (blockIdx.x & 7) << 7;
  const int tid = threadIdx.x, w = tid >> 6, lane = tid & 63;
  const int wr = ((w >> 1) << 6), wc = ((w & 1) << 6);
  const int li = lane & 15, g = lane >> 4;

  f32x4 acc[4][4];
#pragma unroll
  for (int i = 0; i < 4; i++)
#pragma unroll
    for (int j = 0; j < 4; j++) acc[i][j] = (f32x4){0.f, 0.f, 0.f, 0.f};

  for (int k0 = 0; k0 < HDIM; k0 += 64) {
#pragma unroll
    for (int j = 0; j < 4; j++) {
      const int c = w * 4 + j;
      const int r = c * 8 + (lane >> 3);
      const int sc = (lane & 7) ^ (r & 7);
      gload16(A + (size_t)(m0 + r) * HDIM + k0 + sc * 8, (char*)aL + c * 1024);
      gload16(BT + (size_t)(n0 + r) * HDIM + k0 + sc * 8, (char*)bL + c * 1024);
    }
    __syncthreads();
    bf16x8 af[2][4], bfr[2][4];
#pragma unroll
    for (int ks = 0; ks < 2; ks++) {
#pragma unroll
      for (int mf = 0; mf < 4; mf++) {
        const int r = wr + mf * 16 + li;
        const int sl = (g + 4 * ks) ^ (r & 7);
        af[ks][mf] = *(const bf16x8*)((const char*)aL + r * 128 + sl * 16);
      }
#pragma unroll
      for (int nf = 0; nf < 4; nf++) {
        const int r = wc + nf * 16 + li;
        const int sl = (g + 4 * ks) ^ (r & 7);
        bfr[ks][nf] = *(const bf16x8*)((const char*)bL + r * 128 + sl * 16);
      }
    }
    __builtin_amdgcn_s_setprio(1);
#pragma unroll
    for (int ks = 0; ks < 2; ks++)
#pragma unroll
      for (int mf = 0; mf < 4; mf++)
#pragma unroll
        for (int nf = 0; nf < 4; nf++)
          acc[mf][nf] = __builtin_amdgcn_mfma_f32_16x16x32_bf16(
              af[ks][mf], bfr[ks][nf], acc[mf][nf], 0, 0, 0);
    __builtin_amdgcn_s_setprio(0);
    __syncthreads();
  }

#pragma unroll
  for (int mf = 0; mf < 4; mf++)
#pragma unroll
    for (int nf = 0; nf < 4; nf++) {
      const int n = n0 + wc + nf * 16 + li;
      const float bvl = bias[n];
#pragma unroll
      for (int r4 = 0; r4 < 4; r4++) {
        const int m = m0 + wr + mf * 16 + g * 4 + r4;
        C[(size_t)m * HDIM + n] = acc[mf][nf][r4] + bvl;
      }
    }
}

// ---------------- flash attention (R2 structure + T5/T13/XCD swizzle) ------
// block = (b, h, 64 q rows); 4 waves x 16 q rows; KV tiles of 64, dbuf LDS.
// S is in log2 units (0.125*L2E folded into Q projection).
__global__ __launch_bounds__(256, 4) void attn_k(
    const u16* __restrict__ Qp, const u16* __restrict__ Kp,
    const u16* __restrict__ VpT, u16* __restrict__ Hd) {
  __shared__ u16 kbuf[2][64 * 64];
  __shared__ u16 vbuf[2][64 * 64];
  __shared__ u16 pbuf[4][16 * 64];  // per-wave P [q=16][kv=64], XOR-swizzled

  const int bid = blockIdx.x;
  const int swz = (bid & 7) * 128 + (bid >> 3);  // XCD swizzle, bijective
  const int qb = swz & 31;
  const int h = (swz >> 5) & 15;
  const int b = swz >> 9;
  const int tid = threadIdx.x, w = tid >> 6, lane = tid & 63;
  const int li = lane & 15, g = lane >> 4;
  const int q0 = qb << 6;
  const size_t qbase = (size_t)(b * SEQ + q0) * HDIM + (size_t)h * DHD;
  const size_t kbase = (size_t)(b * SEQ) * HDIM + (size_t)h * DHD;
  const size_t vtbase = (size_t)(b * NH + h) * DHD * SEQ;

  const int c0 = w * 2;
  const int rr = lane >> 3;
  const int sc8 = ((lane & 7) ^ ((lane >> 3) & 7)) * 8;

  // ---- stage Q into kbuf[0], read B-fragments ----
#pragma unroll
  for (int j = 0; j < 2; j++) {
    const int c = c0 + j;
    const int r = c * 8 + rr;
    gload16(Qp + qbase + (size_t)r * HDIM + sc8, (char*)kbuf[0] + c * 1024);
  }
  __syncthreads();
  bf16x8 qf[2];
#pragma unroll
  for (int ks = 0; ks < 2; ks++) {
    const int r = w * 16 + li;
    const int sl = (g + 4 * ks) ^ (r & 7);
    qf[ks] = *(const bf16x8*)((const char*)kbuf[0] + r * 128 + sl * 16);
  }
  __syncthreads();

  float mrun = -1e30f, lrun = 0.f;
  f32x4 aco[4];
#pragma unroll
  for (int i = 0; i < 4; i++) aco[i] = (f32x4){0.f, 0.f, 0.f, 0.f};

  char* pw = (char*)pbuf[w] + li * 128;
  const int psw = (li & 7) << 4;

  auto stageKV = [&](int t, int buf) {
    const size_t kb = kbase + (size_t)(t * 64) * HDIM;
    const size_t vb = vtbase + (size_t)(t * 64);
#pragma unroll
    for (int j = 0; j < 2; j++) {
      const int c = c0 + j;
      const int r = c * 8 + rr;
      gload16(Kp + kb + (size_t)r * HDIM + sc8, (char*)kbuf[buf] + c * 1024);
      gload16(VpT + vb + (size_t)r * SEQ + sc8, (char*)vbuf[buf] + c * 1024);
    }
  };

  stageKV(0, 0);

  for (int t = 0; t < SEQ / 64; t++) {
    __syncthreads();
    const int cur = t & 1;
    if (t + 1 < SEQ / 64) stageKV(t + 1, cur ^ 1);

    // ---- S^T = K @ Q^T : lane holds S[q=li][kv = 16c+4g+reg] (log2 units) --
    const char* kl = (const char*)kbuf[cur];
    f32x4 s[4];
#pragma unroll
    for (int c = 0; c < 4; c++) s[c] = (f32x4){0.f, 0.f, 0.f, 0.f};
    __builtin_amdgcn_s_setprio(1);
#pragma unroll
    for (int ks = 0; ks < 2; ks++)
#pragma unroll
      for (int c = 0; c < 4; c++) {
        const int r = c * 16 + li;
        const int sl = (g + 4 * ks) ^ (r & 7);
        const bf16x8 kf = *(const bf16x8*)(kl + r * 128 + sl * 16);
        s[c] = __builtin_amdgcn_mfma_f32_16x16x32_bf16(kf, qf[ks], s[c], 0, 0, 0);
      }
    __builtin_amdgcn_s_setprio(0);

    // ---- online softmax with defer-max (THR=8 in log2 units) ----
    float mx = s[0][0];
#pragma unroll
    for (int c = 0; c < 4; c++)
#pragma unroll
      for (int r4 = 0; r4 < 4; r4++) mx = fmaxf(mx, s[c][r4]);
    mx = fmaxf(mx, __shfl_xor(mx, 16));
    mx = fmaxf(mx, __shfl_xor(mx, 32));
    if (!__all(mx <= mrun + 8.0f)) {
      const float mnew = fmaxf(mrun, mx);
      const float scl = exp2f(mrun - mnew);
      mrun = mnew;
      lrun *= scl;
#pragma unroll
      for (int nf = 0; nf < 4; nf++)
#pragma unroll
        for (int r4 = 0; r4 < 4; r4++) aco[nf][r4] *= scl;
    }
    float p[4][4];
    float rs = 0.f;
#pragma unroll
    for (int c = 0; c < 4; c++)
#pragma unroll
      for (int r4 = 0; r4 < 4; r4++) {
        p[c][r4] = exp2f(s[c][r4] - mrun);
        rs += p[c][r4];
      }
    rs += __shfl_xor(rs, 16);
    rs += __shfl_xor(rs, 32);
    lrun += rs;

    // ---- P -> per-wave LDS (swizzled b64 writes) ----
#pragma unroll
    for (int c = 0; c < 4; c++) {
      uint2 d2;
      d2.x = pack2bf(p[c][0], p[c][1]);
      d2.y = pack2bf(p[c][2], p[c][3]);
      *(uint2*)(pw + ((32 * c + 8 * g) ^ psw)) = d2;
    }

    // ---- O^T += V^T @ P^T ----
    const char* vl = (const char*)vbuf[cur];
    __builtin_amdgcn_s_setprio(1);
#pragma unroll
    for (int ks = 0; ks < 2; ks++) {
      const bf16x8 pf = *(const bf16x8*)(pw + ((64 * ks + 16 * g) ^ psw));
#pragma unroll
      for (int nf = 0; nf < 4; nf++) {
        const int r = nf * 16 + li;
        const int sl = (g + 4 * ks) ^ (r & 7);
        const bf16x8 vf = *(const bf16x8*)(vl + r * 128 + sl * 16);
        aco[nf] = __builtin_amdgcn_mfma_f32_16x16x32_bf16(vf, pf, aco[nf], 0, 0, 0);
      }
    }
    __builtin_amdgcn_s_setprio(0);
  }

  // ---- normalize + write heads ----
  const float inv = 1.f / lrun;
  const int q = q0 + w * 16 + li;
  u16* orow = Hd + (size_t)(b * SEQ + q) * HDIM + (size_t)h * DHD;
#pragma unroll
  for (int nf = 0; nf < 4; nf++) {
    ushort4 o;
    o.x = f2bf(aco[nf][0] * inv);
    o.y = f2bf(aco[nf][1] * inv);
    o.z = f2bf(aco[nf][2] * inv);
    o.w = f2bf(aco[nf][3] * inv);
    *(ushort4*)(orow + nf * 16 + g * 4) = o;
  }
}

// ---------------- launch ----------------
extern "C" void kernel_launch(void* const* d_in, const int* in_sizes, int n_in,
                              void* d_out, int out_size, void* d_ws, size_t ws_size,
                              hipStream_t stream) {
  (void)in_sizes; (void)n_in; (void)out_size; (void)ws_size;
  const float* q_in = (const float*)d_in[0];
  const float* k_in = (const float*)d_in[1];
  const float* v_in = (const float*)d_in[2];
  const float* Wq_w = (const float*)d_in[3];
  const float* Wq_b = (const float*)d_in[4];
  const float* Wk_w = (const float*)d_in[5];
  const float* Wk_b = (const float*)d_in[6];
  const float* Wv_w = (const float*)d_in[7];
  const float* Wv_b = (const float*)d_in[8];
  const float* Wo_w = (const float*)d_in[9];
  const float* Wo_b = (const float*)d_in[10];

  char* ws = (char*)d_ws;
  size_t off = 0;
  auto alloc = [&](size_t n) {
    char* p = ws + off;
    off += (n + 255) & ~(size_t)255;
    return p;
  };
  u16* qkv = (u16*)alloc((size_t)3 * MR * FS * 2);   // q,k,v bf16 contiguous
  u16* wT = (u16*)alloc((size_t)4 * FS * HDIM * 2);  // WqT,WkT,WvT,WoT
  u16* QK = (u16*)alloc((size_t)2 * MR * HDIM * 2);  // Qp,Kp contiguous
  u16* VpT = (u16*)alloc((size_t)MR * HDIM * 2);
  u16* Hdp = (u16*)alloc((size_t)MR * HDIM * 2);

  const int n4 = MR * FS / 4;  // 1<<20
  cast3_k<<<3072, 256, 0, stream>>>(q_in, k_in, v_in, qkv, n4);

  transw4_k<<<dim3(FS / 32, FS / 32, 4), dim3(32, 8), 0, stream>>>(
      Wq_w, Wk_w, Wv_w, Wo_w, wT);

  gemmQKV_k<<<dim3(256, 3), 256, 0, stream>>>(qkv, wT, Wq_b, Wk_b, Wv_b, QK,
                                              VpT);

  attn_k<<<BSZ * NH * (SEQ / 64), 256, 0, stream>>>(
      QK, QK + (size_t)MR * HDIM, VpT, Hdp);

  gemm_out_k<<<256, 256, 0, stream>>>(Hdp, wT + (size_t)3 * FS * HDIM, Wo_b,
                                      (float*)d_out);
}

// Round 5
// 133.357 us; speedup vs baseline: 1.4663x; 1.1199x over previous
//
#include <hip/hip_runtime.h>

#define BSZ 2
#define SEQ 2048
#define NH 16
#define DHD 64
#define HDIM 1024   // NH*DHD
#define FS 1024     // input feature size
#define MR (BSZ*SEQ) // 4096
#define L2E 1.4426950408889634f

typedef __bf16 bf16x8 __attribute__((ext_vector_type(8)));
typedef __bf16 bf16x2t __attribute__((ext_vector_type(2)));
typedef float f32x4 __attribute__((ext_vector_type(4)));
typedef float f32x16 __attribute__((ext_vector_type(16)));
typedef unsigned short u16;
typedef unsigned int u32;

__device__ __forceinline__ u16 f2bf(float f) {
  u32 x = __float_as_uint(f);
  return (u16)((x + 0x7fffu + ((x >> 16) & 1u)) >> 16);
}

__device__ __forceinline__ u32 pack2bf(float a, float b) {
  bf16x2t t = {(__bf16)a, (__bf16)b};
  return __builtin_bit_cast(u32, t);
}

__device__ __forceinline__ void gload16(const void* g, void* l) {
  __builtin_amdgcn_global_load_lds(
      (const __attribute__((address_space(1))) u32*)g,
      (__attribute__((address_space(3))) u32*)l, 16, 0, 0);
}

// ---------------- cast q,k,v fp32 -> bf16 (one launch; dsts contiguous) ----
__global__ __launch_bounds__(256) void cast3_k(const float* __restrict__ q,
                                               const float* __restrict__ k,
                                               const float* __restrict__ v,
                                               u16* __restrict__ dst, int n4) {
  int i = blockIdx.x * 256 + threadIdx.x;
  const int st = gridDim.x * 256;
  const int tot = 3 * n4;
  for (; i < tot; i += st) {
    const int arr = i >> 20;        // n4 == 1<<20
    const int idx = i & (n4 - 1);
    const float* src = arr == 0 ? q : arr == 1 ? k : v;
    float4 vv = ((const float4*)src)[idx];
    ushort4 o;
    o.x = f2bf(vv.x); o.y = f2bf(vv.y); o.z = f2bf(vv.z); o.w = f2bf(vv.w);
    ((ushort4*)dst)[i] = o;
  }
}

// ------- 4x W[K][N] fp32 -> WT[N][K] bf16 (one launch; dsts contiguous) ----
__global__ __launch_bounds__(256) void transw4_k(
    const float* __restrict__ W0, const float* __restrict__ W1,
    const float* __restrict__ W2, const float* __restrict__ W3,
    u16* __restrict__ WTbase) {
  __shared__ float t[32][33];
  const int z = blockIdx.z;
  const float* W = z == 0 ? W0 : z == 1 ? W1 : z == 2 ? W2 : W3;
  u16* WT = WTbase + (size_t)z * FS * HDIM;
  const int tx = threadIdx.x, ty = threadIdx.y;
  const int c0 = blockIdx.x * 32, r0 = blockIdx.y * 32;
#pragma unroll
  for (int i = 0; i < 4; i++)
    t[ty + 8 * i][tx] = W[(size_t)(r0 + ty + 8 * i) * FS + c0 + tx];
  __syncthreads();
#pragma unroll
  for (int i = 0; i < 4; i++)
    WT[(size_t)(c0 + ty + 8 * i) * FS + r0 + tx] = f2bf(t[tx][ty + 8 * i]);
}

// -------- grouped QKV projection GEMM: grid (256, 3) --------
// grp 0: Qp = (q@Wq + bq) * 0.125*L2E  (bf16, [m][n])
// grp 1: Kp = k@Wk + bk                (bf16, [m][n])
// grp 2: VpT = transpose-per-head of (v@Wv + bv)  (bf16, [(b,h,d)][kv])
__global__ __launch_bounds__(256, 2) void gemmQKV_k(
    const u16* __restrict__ Abase, const u16* __restrict__ WTbase,
    const float* __restrict__ bq, const float* __restrict__ bk,
    const float* __restrict__ bv, u16* __restrict__ QKbase,
    u16* __restrict__ VpT) {
  __shared__ u16 aL[128 * 64];
  __shared__ u16 bL[128 * 64];
  const int grp = blockIdx.y;
  const u16* A = Abase + (size_t)grp * MR * FS;
  const u16* BT = WTbase + (size_t)grp * FS * HDIM;
  const float* bias = grp == 0 ? bq : grp == 1 ? bk : bv;
  const int m0 = (blockIdx.x >> 3) << 7;
  const int n0 = (blockIdx.x & 7) << 7;
  const int tid = threadIdx.x, w = tid >> 6, lane = tid & 63;
  const int wr = ((w >> 1) << 6), wc = ((w & 1) << 6);
  const int li = lane & 15, g = lane >> 4;

  f32x4 acc[4][4];
#pragma unroll
  for (int i = 0; i < 4; i++)
#pragma unroll
    for (int j = 0; j < 4; j++) acc[i][j] = (f32x4){0.f, 0.f, 0.f, 0.f};

  for (int k0 = 0; k0 < FS; k0 += 64) {
#pragma unroll
    for (int j = 0; j < 4; j++) {
      const int c = w * 4 + j;
      const int r = c * 8 + (lane >> 3);
      const int sc = (lane & 7) ^ (r & 7);
      gload16(A + (size_t)(m0 + r) * FS + k0 + sc * 8, (char*)aL + c * 1024);
      gload16(BT + (size_t)(n0 + r) * FS + k0 + sc * 8, (char*)bL + c * 1024);
    }
    __syncthreads();
    bf16x8 af[2][4], bfr[2][4];
#pragma unroll
    for (int ks = 0; ks < 2; ks++) {
#pragma unroll
      for (int mf = 0; mf < 4; mf++) {
        const int r = wr + mf * 16 + li;
        const int sl = (g + 4 * ks) ^ (r & 7);
        af[ks][mf] = *(const bf16x8*)((const char*)aL + r * 128 + sl * 16);
      }
#pragma unroll
      for (int nf = 0; nf < 4; nf++) {
        const int r = wc + nf * 16 + li;
        const int sl = (g + 4 * ks) ^ (r & 7);
        bfr[ks][nf] = *(const bf16x8*)((const char*)bL + r * 128 + sl * 16);
      }
    }
#pragma unroll
    for (int ks = 0; ks < 2; ks++)
#pragma unroll
      for (int mf = 0; mf < 4; mf++)
#pragma unroll
        for (int nf = 0; nf < 4; nf++)
          acc[mf][nf] = __builtin_amdgcn_mfma_f32_16x16x32_bf16(
              af[ks][mf], bfr[ks][nf], acc[mf][nf], 0, 0, 0);
    __syncthreads();
  }

  if (grp < 2) {
    const float osc = grp == 0 ? 0.125f * L2E : 1.0f;
    u16* C = QKbase + (size_t)grp * MR * HDIM;
#pragma unroll
    for (int mf = 0; mf < 4; mf++)
#pragma unroll
      for (int nf = 0; nf < 4; nf++) {
        const int n = n0 + wc + nf * 16 + li;
        const float bvl = bias[n];
#pragma unroll
        for (int r4 = 0; r4 < 4; r4++) {
          const int m = m0 + wr + mf * 16 + g * 4 + r4;
          C[(size_t)m * HDIM + n] = f2bf((acc[mf][nf][r4] + bvl) * osc);
        }
      }
  } else {
    // V: write transposed per head -> VpT[((b*NH+h)*DHD+d)][kv]
#pragma unroll
    for (int mf = 0; mf < 4; mf++)
#pragma unroll
      for (int nf = 0; nf < 4; nf++) {
        const int n = n0 + wc + nf * 16 + li;
        const float bvl = bias[n];
        const int m = m0 + wr + mf * 16 + g * 4;
        const int bb = m >> 11, kv = m & 2047;
        ushort4 o;
        o.x = f2bf(acc[mf][nf][0] + bvl);
        o.y = f2bf(acc[mf][nf][1] + bvl);
        o.z = f2bf(acc[mf][nf][2] + bvl);
        o.w = f2bf(acc[mf][nf][3] + bvl);
        *(ushort4*)(VpT +
                    ((size_t)(bb * NH + (n >> 6)) * DHD + (n & 63)) * SEQ + kv) = o;
      }
  }
}

// ---------------- output GEMM: out[M][N] = Hd @ WoT^T + bo (fp32) ----------
__global__ __launch_bounds__(256, 2) void gemm_out_k(
    const u16* __restrict__ A, const u16* __restrict__ BT,
    const float* __restrict__ bias, float* __restrict__ C) {
  __shared__ u16 aL[128 * 64];
  __shared__ u16 bL[128 * 64];
  const int m0 = (blockIdx.x >> 3) << 7;
  const int n0 = (blockIdx.x & 7) << 7;
  const int tid = threadIdx.x, w = tid >> 6, lane = tid & 63;
  const int wr = ((w >> 1) << 6), wc = ((w & 1) << 6);
  const int li = lane & 15, g = lane >> 4;

  f32x4 acc[4][4];
#pragma unroll
  for (int i = 0; i < 4; i++)
#pragma unroll
    for (int j = 0; j < 4; j++) acc[i][j] = (f32x4){0.f, 0.f, 0.f, 0.f};

  for (int k0 = 0; k0 < HDIM; k0 += 64) {
#pragma unroll
    for (int j = 0; j < 4; j++) {
      const int c = w * 4 + j;
      const int r = c * 8 + (lane >> 3);
      const int sc = (lane & 7) ^ (r & 7);
      gload16(A + (size_t)(m0 + r) * HDIM + k0 + sc * 8, (char*)aL + c * 1024);
      gload16(BT + (size_t)(n0 + r) * HDIM + k0 + sc * 8, (char*)bL + c * 1024);
    }
    __syncthreads();
    bf16x8 af[2][4], bfr[2][4];
#pragma unroll
    for (int ks = 0; ks < 2; ks++) {
#pragma unroll
      for (int mf = 0; mf < 4; mf++) {
        const int r = wr + mf * 16 + li;
        const int sl = (g + 4 * ks) ^ (r & 7);
        af[ks][mf] = *(const bf16x8*)((const char*)aL + r * 128 + sl * 16);
      }
#pragma unroll
      for (int nf = 0; nf < 4; nf++) {
        const int r = wc + nf * 16 + li;
        const int sl = (g + 4 * ks) ^ (r & 7);
        bfr[ks][nf] = *(const bf16x8*)((const char*)bL + r * 128 + sl * 16);
      }
    }
#pragma unroll
    for (int ks = 0; ks < 2; ks++)
#pragma unroll
      for (int mf = 0; mf < 4; mf++)
#pragma unroll
        for (int nf = 0; nf < 4; nf++)
          acc[mf][nf] = __builtin_amdgcn_mfma_f32_16x16x32_bf16(
              af[ks][mf], bfr[ks][nf], acc[mf][nf], 0, 0, 0);
    __syncthreads();
  }

#pragma unroll
  for (int mf = 0; mf < 4; mf++)
#pragma unroll
    for (int nf = 0; nf < 4; nf++) {
      const int n = n0 + wc + nf * 16 + li;
      const float bvl = bias[n];
#pragma unroll
      for (int r4 = 0; r4 < 4; r4++) {
        const int m = m0 + wr + mf * 16 + g * 4 + r4;
        C[(size_t)m * HDIM + n] = acc[mf][nf][r4] + bvl;
      }
    }
}

// ---------------- flash attention: 32x32 MFMA, QBLK=128 --------------------
// block = (b, h, 128 q rows); 4 waves x 32 q; KV tiles of 64, dbuf LDS.
// Swapped QK^T: lane owns q = lane&31, 32 kv values in 2 C-tiles.
// S in log2 units (0.125*L2E folded into Q projection).
__global__ __launch_bounds__(256, 2) void attn_k(
    const u16* __restrict__ Qp, const u16* __restrict__ Kp,
    const u16* __restrict__ VpT, u16* __restrict__ Hd) {
  __shared__ u16 kbuf[2][64 * 64];   // K [kv][d], swizzled; also Q staging
  __shared__ u16 vbuf[2][64 * 64];   // V^T [d][kv], swizzled
  __shared__ u16 pbuf[4][32 * 64];   // per-wave P^T [q][kv], swizzled

  const int bid = blockIdx.x;
  const int swz = (bid & 7) * 64 + (bid >> 3);  // XCD swizzle (512 % 8 == 0)
  const int qb = swz & 15;
  const int h = (swz >> 4) & 15;
  const int b = swz >> 8;
  const int tid = threadIdx.x, w = tid >> 6, lane = tid & 63;
  const int q32 = lane & 31, hi = lane >> 5;
  const int q0 = qb << 7;
  const size_t qbase = (size_t)(b * SEQ + q0) * HDIM + (size_t)h * DHD;
  const size_t kbase = (size_t)(b * SEQ) * HDIM + (size_t)h * DHD;
  const size_t vtbase = (size_t)(b * NH + h) * DHD * SEQ;

  const int rr = lane >> 3;                 // 0..7
  const int sc8 = ((lane & 7) ^ rr) * 8;    // pre-swizzled source element

  // ---- stage Q (16KB = all of kbuf), read B-fragments, release ----
#pragma unroll
  for (int j = 0; j < 4; j++) {
    const int c = w * 4 + j;                // 16 chunks of 8 rows
    const int r = c * 8 + rr;               // q row 0..127
    gload16(Qp + qbase + (size_t)r * HDIM + sc8, (char*)kbuf + c * 1024);
  }
  __syncthreads();
  bf16x8 qf[4];
  {
    const int qrow = w * 32 + q32;
    const char* qbp = (const char*)kbuf + qrow * 128;
    const int qsw = (qrow & 7) << 4;
#pragma unroll
    for (int ds = 0; ds < 4; ds++)
      qf[ds] = *(const bf16x8*)(qbp + ((32 * ds + 16 * hi) ^ qsw));
  }
  __syncthreads();

  float mrun = -1e30f, lrun = 0.f;
  f32x16 o0, o1;
#pragma unroll
  for (int i = 0; i < 16; i++) { o0[i] = 0.f; o1[i] = 0.f; }

  char* pw = (char*)pbuf[w] + q32 * 128;    // this lane's P^T row
  const int psw = (q32 & 7) << 4;
  const int rsw = psw;                      // (q32&7)<<4 == ((32+q32)&7)<<4

  auto stageKV = [&](int t, int buf) {
    const size_t kb = kbase + (size_t)(t * 64) * HDIM;
    const size_t vb = vtbase + (size_t)(t * 64);
#pragma unroll
    for (int j = 0; j < 2; j++) {
      const int c = w * 2 + j;
      const int r = c * 8 + rr;
      gload16(Kp + kb + (size_t)r * HDIM + sc8, (char*)kbuf[buf] + c * 1024);
      gload16(VpT + vb + (size_t)r * SEQ + sc8, (char*)vbuf[buf] + c * 1024);
    }
  };

  auto TILE = [&](int t, int par) {
    __syncthreads();                         // stage(t) drained, reads done
    if (t + 1 < SEQ / 64) stageKV(t + 1, par ^ 1);
    const char* kl = (const char*)kbuf[par];
    const char* vl = (const char*)vbuf[par];

    // ---- S^T = K @ Q^T : C[kv 0-31 | 32-63][q], col=q32 ----
    f32x16 s0, s1;
#pragma unroll
    for (int i = 0; i < 16; i++) { s0[i] = 0.f; s1[i] = 0.f; }
#pragma unroll
    for (int ds = 0; ds < 4; ds++) {
      const int off = (32 * ds + 16 * hi) ^ rsw;
      const bf16x8 ka = *(const bf16x8*)(kl + q32 * 128 + off);
      const bf16x8 kb2 = *(const bf16x8*)(kl + (32 + q32) * 128 + off);
      s0 = __builtin_amdgcn_mfma_f32_32x32x16_bf16(ka, qf[ds], s0, 0, 0, 0);
      s1 = __builtin_amdgcn_mfma_f32_32x32x16_bf16(kb2, qf[ds], s1, 0, 0, 0);
    }

    // ---- online softmax with defer-max (THR=8, log2 units) ----
    float mx = s0[0];
#pragma unroll
    for (int i = 1; i < 16; i++) mx = fmaxf(mx, s0[i]);
#pragma unroll
    for (int i = 0; i < 16; i++) mx = fmaxf(mx, s1[i]);
    mx = fmaxf(mx, __shfl_xor(mx, 32));
    if (!__all(mx <= mrun + 8.0f)) {
      const float mnew = fmaxf(mrun, mx);
      const float scl = __builtin_amdgcn_exp2f(mrun - mnew);
      mrun = mnew;
      lrun *= scl;
#pragma unroll
      for (int i = 0; i < 16; i++) { o0[i] *= scl; o1[i] *= scl; }
    }
    float p0[16], p1[16];
    float rs = 0.f;
#pragma unroll
    for (int i = 0; i < 16; i++) {
      p0[i] = __builtin_amdgcn_exp2f(s0[i] - mrun);
      p1[i] = __builtin_amdgcn_exp2f(s1[i] - mrun);
      rs += p0[i] + p1[i];
    }
    rs += __shfl_xor(rs, 32);
    lrun += rs;

    // ---- P -> per-wave LDS (swizzled b64 writes) ----
#pragma unroll
    for (int rg = 0; rg < 4; rg++) {
      uint2 a2, b2;
      a2.x = pack2bf(p0[4 * rg + 0], p0[4 * rg + 1]);
      a2.y = pack2bf(p0[4 * rg + 2], p0[4 * rg + 3]);
      b2.x = pack2bf(p1[4 * rg + 0], p1[4 * rg + 1]);
      b2.y = pack2bf(p1[4 * rg + 2], p1[4 * rg + 3]);
      *(uint2*)(pw + ((16 * rg + 8 * hi) ^ psw)) = a2;
      *(uint2*)(pw + ((64 + 16 * rg + 8 * hi) ^ psw)) = b2;
    }

    // ---- O^T += V^T @ P^T : C[d 0-31 | 32-63][q] ----
#pragma unroll
    for (int kvs = 0; kvs < 4; kvs++) {
      const int off = (32 * kvs + 16 * hi);
      const bf16x8 pf = *(const bf16x8*)(pw + (off ^ psw));
      const bf16x8 va = *(const bf16x8*)(vl + q32 * 128 + (off ^ rsw));
      const bf16x8 vb2 = *(const bf16x8*)(vl + (32 + q32) * 128 + (off ^ rsw));
      o0 = __builtin_amdgcn_mfma_f32_32x32x16_bf16(va, pf, o0, 0, 0, 0);
      o1 = __builtin_amdgcn_mfma_f32_32x32x16_bf16(vb2, pf, o1, 0, 0, 0);
    }
  };

  stageKV(0, 0);
#pragma unroll 1
  for (int tt = 0; tt < SEQ / 128; tt++) {
    TILE(2 * tt, 0);
    TILE(2 * tt + 1, 1);
  }

  // ---- normalize + write: lane owns q = q0 + w*32 + q32 ----
  const float inv = 1.f / lrun;
  const int q = q0 + w * 32 + q32;
  u16* orow = Hd + (size_t)(b * SEQ + q) * HDIM + (size_t)h * DHD;
#pragma unroll
  for (int rg = 0; rg < 4; rg++) {
    ushort4 ov;
    ov.x = f2bf(o0[4 * rg + 0] * inv);
    ov.y = f2bf(o0[4 * rg + 1] * inv);
    ov.z = f2bf(o0[4 * rg + 2] * inv);
    ov.w = f2bf(o0[4 * rg + 3] * inv);
    *(ushort4*)(orow + 8 * rg + 4 * hi) = ov;
    ushort4 ow;
    ow.x = f2bf(o1[4 * rg + 0] * inv);
    ow.y = f2bf(o1[4 * rg + 1] * inv);
    ow.z = f2bf(o1[4 * rg + 2] * inv);
    ow.w = f2bf(o1[4 * rg + 3] * inv);
    *(ushort4*)(orow + 32 + 8 * rg + 4 * hi) = ow;
  }
}

// ---------------- launch ----------------
extern "C" void kernel_launch(void* const* d_in, const int* in_sizes, int n_in,
                              void* d_out, int out_size, void* d_ws, size_t ws_size,
                              hipStream_t stream) {
  (void)in_sizes; (void)n_in; (void)out_size; (void)ws_size;
  const float* q_in = (const float*)d_in[0];
  const float* k_in = (const float*)d_in[1];
  const float* v_in = (const float*)d_in[2];
  const float* Wq_w = (const float*)d_in[3];
  const float* Wq_b = (const float*)d_in[4];
  const float* Wk_w = (const float*)d_in[5];
  const float* Wk_b = (const float*)d_in[6];
  const float* Wv_w = (const float*)d_in[7];
  const float* Wv_b = (const float*)d_in[8];
  const float* Wo_w = (const float*)d_in[9];
  const float* Wo_b = (const float*)d_in[10];

  char* ws = (char*)d_ws;
  size_t off = 0;
  auto alloc = [&](size_t n) {
    char* p = ws + off;
    off += (n + 255) & ~(size_t)255;
    return p;
  };
  u16* qkv = (u16*)alloc((size_t)3 * MR * FS * 2);   // q,k,v bf16 contiguous
  u16* wT = (u16*)alloc((size_t)4 * FS * HDIM * 2);  // WqT,WkT,WvT,WoT
  u16* QK = (u16*)alloc((size_t)2 * MR * HDIM * 2);  // Qp,Kp contiguous
  u16* VpT = (u16*)alloc((size_t)MR * HDIM * 2);
  u16* Hdp = (u16*)alloc((size_t)MR * HDIM * 2);

  const int n4 = MR * FS / 4;  // 1<<20
  cast3_k<<<3072, 256, 0, stream>>>(q_in, k_in, v_in, qkv, n4);

  transw4_k<<<dim3(FS / 32, FS / 32, 4), dim3(32, 8), 0, stream>>>(
      Wq_w, Wk_w, Wv_w, Wo_w, wT);

  gemmQKV_k<<<dim3(256, 3), 256, 0, stream>>>(qkv, wT, Wq_b, Wk_b, Wv_b, QK,
                                              VpT);

  attn_k<<<BSZ * NH * (SEQ / 128), 256, 0, stream>>>(
      QK, QK + (size_t)MR * HDIM, VpT, Hdp);

  gemm_out_k<<<256, 256, 0, stream>>>(Hdp, wT + (size_t)3 * FS * HDIM, Wo_b,
                                      (float*)d_out);
}